// Round 11
// baseline (6425.765 us; speedup 1.0000x reference)
//
#include <hip/hip_runtime.h>

#define BATCH    128
#define NPTS     32768
#define HALFN    (NPTS / 2)          // 16384 points per block
#define KOUT     1024
#define NTHREADS 512
#define PPT      (HALFN / NTHREADS)  // 32 points per thread (md regs)
#define NREG     4096                // points with coords in registers
#define RPT      (NREG / NTHREADS)   // 8 reg points per thread
#define NLDS     (HALFN - NREG)      // 12288 points with coords in LDS
#define NGRP     (NLDS / (NTHREADS * 4))  // 6 float4 groups per thread

// Pair mailbox, DOUBLE-BUFFERED by iteration parity. The handshake allows a
// block to run at most 1 iteration ahead of its partner; with a single slot
// that lets iteration j+1's post overwrite iteration j's data while the
// (momentarily stalled) partner is still reading it -> the R10 failure.
// With slot[j&1]: the writer reuses slot (j&1) at iteration j+2, gated on
// partner seq >= j+1, and the partner posts seq=j+1 only AFTER it finished
// reading slot j. Data is never overwritten before it is read.
struct __align__(16) Slot {
    unsigned long long key[2];  // (val_bits<<32) | (0xffffffff - global_idx)
    float cx[2], cy[2], cz[2];
    unsigned int       seq;     // last iteration posted (monotonic)
};
#define SLOT_STRIDE 128
#define WS_NEEDED   (256 * SLOT_STRIDE)

// 2 blocks per batch (grid 256 = every CU). mindist lives in 32 VGPRs
// (loop-carried -> not rematerializable), coords live 4096-in-regs +
// 12288-in-static-LDS (float4 ds_read_b128). 144 KiB static LDS forces
// 1 block/CU so the allocator grants 128 VGPRs (measured R6/R7); pressure
// ~90 -> no spill. Zero LDS writes and zero global reads in the inner loop.
__global__ __launch_bounds__(NTHREADS)
void fps_pair_kernel(const float* __restrict__ x, float* __restrict__ out,
                     char* __restrict__ ws) {
    __shared__ __align__(16) float lx[NLDS];   // 48 KiB
    __shared__ __align__(16) float ly[NLDS];   // 48 KiB
    __shared__ __align__(16) float lz[NLDS];   // 48 KiB
    __shared__ float s_redv[8];
    __shared__ int   s_redi[8];
    __shared__ float s_pt[3];

    const int bid  = blockIdx.x;
    const int b    = bid & (BATCH - 1);
    const int half = bid >> 7;              // 0: pts [0,16384), 1: rest
    const int tid  = threadIdx.x;
    const int base = half * HALFN;

    const float* __restrict__ xb = x + (size_t)b * 3 * NPTS;
    float* __restrict__ ob = out + (size_t)b * 3 * KOUT;

    Slot* myslot = (Slot*)(ws + (size_t)bid * SLOT_STRIDE);
    Slot* paslot = (Slot*)(ws + (size_t)(bid ^ 128) * SLOT_STRIDE);

    // Register coords: local ids [0, 4096), thread owns tid + i*512.
    float xs[RPT], ys[RPT], zs[RPT];
#pragma unroll
    for (int i = 0; i < RPT; ++i) {
        const int g = base + tid + i * NTHREADS;
        xs[i] = xb[g];
        ys[i] = xb[NPTS + g];
        zs[i] = xb[2 * NPTS + g];
    }
    // LDS coords: local ids [4096, 16384) -> planes lx/ly/lz[p], p=lid-4096.
#pragma unroll
    for (int k = 0; k < NLDS / NTHREADS; ++k) {
        const int p = tid + k * NTHREADS;
        const int g = base + NREG + p;
        lx[p] = xb[g];
        ly[p] = xb[NPTS + g];
        lz[p] = xb[2 * NPTS + g];
    }
    // Per-point mindist in registers: md[0..7] = reg pts, md[8..31] = LDS pts.
    float md[PPT];
#pragma unroll
    for (int i = 0; i < PPT; ++i) md[i] = 1e10f;

    // First selected point is global index 0.
    float px = xb[0], py = xb[NPTS], pz = xb[2 * NPTS];
    if (half == 0 && tid == 0) {
        ob[0] = px; ob[KOUT] = py; ob[2 * KOUT] = pz;
    }
    __syncthreads();

    const int lane = tid & 63;
    const int wave = tid >> 6;
    const float4* lx4 = (const float4*)lx;
    const float4* ly4 = (const float4*)ly;
    const float4* lz4 = (const float4*)lz;

    for (int j = 1; j < KOUT; ++j) {
        float best = -1.0f;
        int   bi   = 0x7fffffff;

        // ---- register points (local ids ascending: tid + i*512 < 4096) ----
        // Bit-exact vs reference (verified rounds 2-9, absmax 0):
        //   d = fma(dz,dz, fma(dy,dy, rn(dx*dx)))
#pragma unroll
        for (int i = 0; i < RPT; ++i) {
            const float dx = __fsub_rn(xs[i], px);
            const float dy = __fsub_rn(ys[i], py);
            const float dz = __fsub_rn(zs[i], pz);
            const float d  = __fmaf_rn(dz, dz,
                              __fmaf_rn(dy, dy,
                                __fmul_rn(dx, dx)));
            const float m  = fminf(md[i], d);
            md[i] = m;
            if (m > best) { best = m; bi = tid + i * NTHREADS; }
        }
        // ---- LDS points (local ids 4096 + w*2048 + tid*4 + q, ascending) ----
#pragma unroll
        for (int w = 0; w < NGRP; ++w) {
            const float4 cx = lx4[w * NTHREADS + tid];
            const float4 cy = ly4[w * NTHREADS + tid];
            const float4 cz = lz4[w * NTHREADS + tid];
#pragma unroll
            for (int q = 0; q < 4; ++q) {
                const int i = RPT + w * 4 + q;          // md register index
                const float vx = (q == 0) ? cx.x : (q == 1) ? cx.y
                               : (q == 2) ? cx.z : cx.w;
                const float vy = (q == 0) ? cy.x : (q == 1) ? cy.y
                               : (q == 2) ? cy.z : cy.w;
                const float vz = (q == 0) ? cz.x : (q == 1) ? cz.y
                               : (q == 2) ? cz.z : cz.w;
                const float dx = __fsub_rn(vx, px);
                const float dy = __fsub_rn(vy, py);
                const float dz = __fsub_rn(vz, pz);
                const float d  = __fmaf_rn(dz, dz,
                                  __fmaf_rn(dy, dy,
                                    __fmul_rn(dx, dx)));
                const float m  = fminf(md[i], d);
                md[i] = m;
                if (m > best) { best = m; bi = NREG + w * 2048 + tid * 4 + q; }
            }
        }

        // Wave butterfly argmax (tie -> smaller local index).
#pragma unroll
        for (int s = 1; s < 64; s <<= 1) {
            const float ov = __shfl_xor(best, s, 64);
            const int   oi = __shfl_xor(bi,   s, 64);
            if (ov > best || (ov == best && oi < bi)) { best = ov; bi = oi; }
        }
        if (lane == 0) { s_redv[wave] = best; s_redi[wave] = bi; }
        __syncthreads();

        if (wave == 0) {
            float v  = (lane < 8) ? s_redv[lane] : -1.0f;
            int   vi = (lane < 8) ? s_redi[lane] : 0x7fffffff;
#pragma unroll
            for (int s = 1; s < 8; s <<= 1) {
                const float ov = __shfl_xor(v,  s, 64);
                const int   oi = __shfl_xor(vi, s, 64);
                if (ov > v || (ov == v && oi < vi)) { v = ov; vi = oi; }
            }
            if (lane == 0) {
                // Candidate coords: LDS for lid>=4096 (75%), global else.
                float ccx, ccy, ccz;
                if (vi >= NREG) {
                    const int p = vi - NREG;
                    ccx = lx[p]; ccy = ly[p]; ccz = lz[p];
                } else {
                    const int g = base + vi;
                    ccx = xb[g]; ccy = xb[NPTS + g]; ccz = xb[2 * NPTS + g];
                }
                const int gidx = base + vi;
                const int sl   = j & 1;       // double-buffer slot index
                // key max == (max val, tie -> min global idx); d >= 0 so
                // float bit order == value order.
                const unsigned long long key =
                    ((unsigned long long)__float_as_uint(v) << 32) |
                    (unsigned long long)(0xffffffffu - (unsigned)gidx);
                __hip_atomic_store(&myslot->key[sl], key,
                                   __ATOMIC_RELAXED, __HIP_MEMORY_SCOPE_AGENT);
                __hip_atomic_store(&myslot->cx[sl], ccx,
                                   __ATOMIC_RELAXED, __HIP_MEMORY_SCOPE_AGENT);
                __hip_atomic_store(&myslot->cy[sl], ccy,
                                   __ATOMIC_RELAXED, __HIP_MEMORY_SCOPE_AGENT);
                __hip_atomic_store(&myslot->cz[sl], ccz,
                                   __ATOMIC_RELAXED, __HIP_MEMORY_SCOPE_AGENT);
                __hip_atomic_store(&myslot->seq, (unsigned)j,
                                   __ATOMIC_RELEASE, __HIP_MEMORY_SCOPE_AGENT);
                while (__hip_atomic_load(&paslot->seq, __ATOMIC_ACQUIRE,
                                         __HIP_MEMORY_SCOPE_AGENT) < (unsigned)j) {}
                const unsigned long long pkey =
                    __hip_atomic_load(&paslot->key[sl],
                                      __ATOMIC_RELAXED, __HIP_MEMORY_SCOPE_AGENT);
                if (pkey > key) {
                    ccx = __hip_atomic_load(&paslot->cx[sl],
                                            __ATOMIC_RELAXED, __HIP_MEMORY_SCOPE_AGENT);
                    ccy = __hip_atomic_load(&paslot->cy[sl],
                                            __ATOMIC_RELAXED, __HIP_MEMORY_SCOPE_AGENT);
                    ccz = __hip_atomic_load(&paslot->cz[sl],
                                            __ATOMIC_RELAXED, __HIP_MEMORY_SCOPE_AGENT);
                }
                s_pt[0] = ccx; s_pt[1] = ccy; s_pt[2] = ccz;
                if (half == 0) {
                    ob[j] = ccx; ob[KOUT + j] = ccy; ob[2 * KOUT + j] = ccz;
                }
            }
        }
        __syncthreads();
        px = s_pt[0]; py = s_pt[1]; pz = s_pt[2];
    }
}

// Emergency fallback (ws too small): proven single-block variant (round 6).
__global__ __launch_bounds__(NTHREADS)
void fps_single_kernel(const float* __restrict__ x, float* __restrict__ out) {
    __shared__ float s_md[NPTS];      // 128 KiB, static
    __shared__ float s_redv[8];
    __shared__ int   s_redi[8];
    __shared__ float s_pt[3];

    const int b   = blockIdx.x;
    const int tid = threadIdx.x;
    const float* __restrict__ xb = x + (size_t)b * 3 * NPTS;
    float* __restrict__ ob = out + (size_t)b * 3 * KOUT;
#define SPPT (NPTS / NTHREADS)
    float xs[SPPT], ys[SPPT], zs[SPPT];
#pragma unroll
    for (int i = 0; i < SPPT; ++i) {
        const int n = tid + i * NTHREADS;
        xs[i] = xb[n]; ys[i] = xb[NPTS + n]; zs[i] = xb[2 * NPTS + n];
        s_md[n] = 1e10f;
    }
    float px = xb[0], py = xb[NPTS], pz = xb[2 * NPTS];
    if (tid == 0) { ob[0] = px; ob[KOUT] = py; ob[2 * KOUT] = pz; }
    __syncthreads();
    const int lane = tid & 63, wave = tid >> 6;
    for (int j = 1; j < KOUT; ++j) {
        float best = -1.0f; int bi = 0x7fffffff;
#pragma unroll
        for (int i = 0; i < SPPT; ++i) {
            const int n = tid + i * NTHREADS;
            const float dx = __fsub_rn(xs[i], px);
            const float dy = __fsub_rn(ys[i], py);
            const float dz = __fsub_rn(zs[i], pz);
            const float d  = __fmaf_rn(dz, dz, __fmaf_rn(dy, dy, __fmul_rn(dx, dx)));
            const float m  = fminf(s_md[n], d);
            s_md[n] = m;
            if (m > best) { best = m; bi = n; }
        }
#pragma unroll
        for (int s = 1; s < 64; s <<= 1) {
            const float ov = __shfl_xor(best, s, 64);
            const int   oi = __shfl_xor(bi,   s, 64);
            if (ov > best || (ov == best && oi < bi)) { best = ov; bi = oi; }
        }
        if (lane == 0) { s_redv[wave] = best; s_redi[wave] = bi; }
        __syncthreads();
        if (wave == 0) {
            float v  = (lane < 8) ? s_redv[lane] : -1.0f;
            int   vi = (lane < 8) ? s_redi[lane] : 0x7fffffff;
#pragma unroll
            for (int s = 1; s < 8; s <<= 1) {
                const float ov = __shfl_xor(v,  s, 64);
                const int   oi = __shfl_xor(vi, s, 64);
                if (ov > v || (ov == v && oi < vi)) { v = ov; vi = oi; }
            }
            if (lane == 0) {
                const float sx = xb[vi], sy = xb[NPTS + vi], sz = xb[2 * NPTS + vi];
                s_pt[0] = sx; s_pt[1] = sy; s_pt[2] = sz;
                ob[j] = sx; ob[KOUT + j] = sy; ob[2 * KOUT + j] = sz;
            }
        }
        __syncthreads();
        px = s_pt[0]; py = s_pt[1]; pz = s_pt[2];
    }
}

extern "C" void kernel_launch(void* const* d_in, const int* in_sizes, int n_in,
                              void* d_out, int out_size, void* d_ws, size_t ws_size,
                              hipStream_t stream) {
    const float* x = (const float*)d_in[0];
    float* out = (float*)d_out;
    if (ws_size >= WS_NEEDED) {
        // Zero the mailboxes every launch (graph-capturable, stream-ordered).
        hipMemsetAsync(d_ws, 0, WS_NEEDED, stream);
        fps_pair_kernel<<<2 * BATCH, NTHREADS, 0, stream>>>(x, out, (char*)d_ws);
    } else {
        fps_single_kernel<<<BATCH, NTHREADS, 0, stream>>>(x, out);
    }
}